// Round 2
// baseline (35.448 us; speedup 1.0000x reference)
//
#include <hip/hip_runtime.h>
#include <cmath>

// SpikesToTimesDecoder: input [T, B, N] fp32 0/1 raster -> output [3, B, N]
// fp32 times (t * 0.001) of the first 3 spikes per channel, inf-padded.
//
// One thread per (b, n) channel; lane i of a wave handles channel base+i, so
// each timestep's 64 lane loads are 256 B contiguous (fully coalesced).
// Per-wave early exit once all 64 lanes have 3 spikes (expected exit t~170
// of 512 at 5% rate) -> skips ~2/3 of the input fetch.
//
// 4-buffer rotating software pipeline, prefetch distance 3 chunks (48 loads
// in flight per thread): hides the ~900-cycle HBM latency that the previous
// issue-drain-process loop ate once per chunk (only 2 waves/SIMD available
// for TLP, and straggler waves run the tail nearly alone).
// Buffers are named static arrays with compile-time indices only ->
// registers, not scratch.

constexpr int K_SPIKES = 3;
constexpr int CHUNK = 16;

__global__ __launch_bounds__(256) void spikes_to_times_kernel(
    const float* __restrict__ in, float* __restrict__ out,
    int BN, int T, float dt) {
  const int c = blockIdx.x * blockDim.x + threadIdx.x;
  if (c >= BN) return;

  const int nchunks = (T + CHUNK - 1) / CHUNK;
  const float* p = in + c;

  float t0 = INFINITY, t1 = INFINITY, t2 = INFINITY;
  int cnt = 0;

  float b0[CHUNK], b1[CHUNK], b2[CHUNK], b3[CHUNK];

  // Issue loads for chunk ci into buffer `dst` (clamped so prefetch past the
  // end reads valid memory; clamped chunks are never processed).
#define LOADC(dst, ci)                                                   \
  do {                                                                   \
    const int cc_ = ((ci) < nchunks) ? (ci) : (nchunks - 1);             \
    _Pragma("unroll") for (int j = 0; j < CHUNK; ++j) {                  \
      dst[j] = p[(size_t)(cc_ * CHUNK + j) * (size_t)BN];                \
    }                                                                    \
  } while (0)

  // Process chunk ci held in buffer `src` (branchless conditional chain).
#define PROC(src, ci)                                                    \
  do {                                                                   \
    if ((ci) < nchunks) {                                                \
      _Pragma("unroll") for (int j = 0; j < CHUNK; ++j) {                \
        const int ti_ = (ci) * CHUNK + j;                                \
        const bool s_ = (src[j] > 0.0f) && (ti_ < T);                    \
        const float tt_ = (float)ti_;                                    \
        if (s_ && cnt == 0) t0 = tt_;                                    \
        if (s_ && cnt == 1) t1 = tt_;                                    \
        if (s_ && cnt == 2) t2 = tt_;                                    \
        cnt += s_ ? 1 : 0;                                               \
      }                                                                  \
    }                                                                    \
  } while (0)

  // Prologue: prefetch chunks 0,1,2.
  LOADC(b0, 0);
  LOADC(b1, 1);
  LOADC(b2, 2);

  // Steady state: each chunk's loads are issued exactly 3 process-steps
  // before consumption. Exit check after every processed chunk.
  for (int base = 0; base < nchunks; base += 4) {
    LOADC(b3, base + 3);
    PROC(b0, base + 0);
    if (__all(cnt >= K_SPIKES)) break;

    LOADC(b0, base + 4);
    PROC(b1, base + 1);
    if (__all(cnt >= K_SPIKES)) break;

    LOADC(b1, base + 5);
    PROC(b2, base + 2);
    if (__all(cnt >= K_SPIKES)) break;

    LOADC(b2, base + 6);
    PROC(b3, base + 3);
    if (__all(cnt >= K_SPIKES)) break;
  }

#undef LOADC
#undef PROC

  out[c]          = t0 * dt;
  out[BN + c]     = t1 * dt;
  out[2 * BN + c] = t2 * dt;
}

extern "C" void kernel_launch(void* const* d_in, const int* in_sizes, int n_in,
                              void* d_out, int out_size, void* d_ws, size_t ws_size,
                              hipStream_t stream) {
  const float* in = (const float*)d_in[0];
  float* out = (float*)d_out;

  const int BN = out_size / K_SPIKES;  // B * N channels
  const int T = in_sizes[0] / BN;      // timesteps

  const int block = 256;
  const int grid = (BN + block - 1) / block;
  hipLaunchKernelGGL(spikes_to_times_kernel, dim3(grid), dim3(block), 0, stream,
                     in, out, BN, T, 0.001f);
}